// Round 8
// baseline (818.109 us; speedup 1.0000x reference)
//
#include <hip/hip_runtime.h>
#include <math.h>

#define NTHREADS 256

__constant__ int c_RESA[8] = {1, 2, 4, 6, 8, 10, 12, 16};
__constant__ int c_OFF6[8] = {0, 6, 30, 126, 342, 726, 1326, 2190};
// ceil(2^20 / R): exact floor-div for t < 2048 (verified for all R here)
__constant__ unsigned c_MAGIC[8] = {1048576u, 524288u, 262144u, 174763u,
                                    131072u, 104858u, 87382u, 65536u};

// Transpose w2 [s][co][ci][j] -> w2T [s][j][ci/4][co][ci%4] : contiguous in
// S3's exact consumption order so weight reads become mergeable s_load runs.
__global__ void __launch_bounds__(256)
prep_w2t_kernel(const float* __restrict__ w2g, float* __restrict__ w2t) {
    int tid = blockIdx.x * blockDim.x + threadIdx.x;
    for (int i = tid; i < 8 * 2592; i += gridDim.x * blockDim.x) {
        int e  = i & 3;
        int r  = i >> 2;
        int co = r % 6;  r /= 6;
        int c4 = r % 12; r /= 12;
        int j  = r % 9;
        int s  = r / 9;
        int ci = c4 * 4 + e;
        w2t[i] = w2g[((size_t)(s * 6 + co) * 48 + ci) * 9 + j];
    }
}

// Bilinear tap, matching jax.image.resize(bilinear, antialias=False).
__device__ __forceinline__ void mk_tap(int o, float invs, int insz,
                                       int* i0, int* i1, float* w0, float* w1) {
    float fy = __fsub_rn(__fmul_rn(__fadd_rn((float)o, 0.5f), invs), 0.5f);
    float fl = floorf(fy);
    int y0 = (int)fl;
    float k0 = __fsub_rn(1.0f, fabsf(__fsub_rn(fy, fl)));
    float k1 = __fsub_rn(1.0f, fabsf(__fsub_rn(fy, __fadd_rn(fl, 1.0f))));
    bool v0 = (y0 >= 0);
    bool v1 = (y0 + 1 <= insz - 1);
    k0 = v0 ? k0 : 0.0f;
    k1 = v1 ? k1 : 0.0f;
    float ssum = __fadd_rn(k0, k1);
    *w0 = __fdiv_rn(k0, ssum);
    *w1 = __fdiv_rn(k1, ssum);
    *i0 = v0 ? y0 : 0;
    *i1 = v1 ? (y0 + 1) : (insz - 1);
}

__device__ __forceinline__ float gelu_exact(float x) {
    // 0.5*x*(1+erf(x*rn(1/sqrt2))): <=1ulp vs fdiv form; proven flip-safe.
    return __fmul_rn(__fmul_rn(0.5f, x),
                     __fadd_rn(1.0f, erff(__fmul_rn(x, 0.70710678118654752440f))));
}

__global__ void __launch_bounds__(NTHREADS)
var_tokenizer_kernel(const float* __restrict__ latents,
                     const float* __restrict__ w1g, const float* __restrict__ b1g,
                     const float* __restrict__ w2t, const float* __restrict__ b2g,
                     float* __restrict__ out) {
    __shared__ float f_l[1536];                      // residual latent 6x16x16
    __shared__ float r_pad[6 * 196];                 // codes, ch-major, zero-padded 14x14
    __shared__ __align__(16) float h4[12 * 196 * 4]; // hidden: [c4-group][pos][4] float4
    __shared__ float z_l[6 * 144];                   // conv2 output (unpadded)
    __shared__ int   dti0[16]; __shared__ int dti1[16];
    __shared__ float dtw0[16]; __shared__ float dtw1[16];
    __shared__ int   uti0[16]; __shared__ int uti1[16];
    __shared__ float utw0[16]; __shared__ float utw1[16];

    const int item = blockIdx.x;
    const int tid  = threadIdx.x;
    const int wv   = __builtin_amdgcn_readfirstlane(tid >> 6); // wave id (uniform)
    const int lane = tid & 63;

    const float* lat  = latents + (size_t)item * 1536;
    float*       outb = out + (size_t)item * 3726;

    for (int i = tid; i < 1536; i += NTHREADS) f_l[i] = lat[i];
    // One-time zero fill (monotonic-resolution argument: border cells of every
    // scale's window are never written non-zero before being read; z lives in
    // separate z_l so h4/r_pad are never polluted).
    for (int i = tid; i < 6 * 196;      i += NTHREADS) r_pad[i] = 0.0f;
    for (int i = tid; i < 12 * 196 * 4; i += NTHREADS) h4[i] = 0.0f;

    // FSQ constants, replicating reference fp32 op order.
    const float HL8 = (8.0f - 1.0f) * (1.0f + 1.0e-3f) / 2.0f;  // 3.5035
    const float HL5 = (5.0f - 1.0f) * (1.0f + 1.0e-3f) / 2.0f;  // 2.002
    const float SH8 = (float)atanh((double)(0.5f / HL8));

    __syncthreads();

    for (int s = 0; s < 8; ++s) {
        const int R  = c_RESA[s];
        const int HW = R * R;
        const unsigned M = c_MAGIC[s];
        const bool last = (s == 7);

        // --- per-scale bilinear tap tables ---
        if (tid < R) {
            float invs = __fdiv_rn(1.0f, __fdiv_rn((float)R, 16.0f));
            mk_tap(tid, invs, 16, &dti0[tid], &dti1[tid], &dtw0[tid], &dtw1[tid]);
        } else if (tid >= 64 && tid < 80 && !last) {
            int o = tid - 64;
            float invs = __fdiv_rn(1.0f, __fdiv_rn(16.0f, (float)R));
            mk_tap(o, invs, R, &uti0[o], &uti1[o], &utw0[o], &utw1[o]);
        }
        __syncthreads();

        // --- S1: resize f -> (R,R), FSQ quantize, emit tokens (+ r_pad) ---
        const int off = c_OFF6[s];
        for (int t = tid; t < 6 * HW; t += NTHREADS) {
            int rest = (int)(((unsigned)t * M) >> 20);      // t / R
            int ox   = t - rest * R;                        // t % R
            int c    = (int)(((unsigned)rest * M) >> 20);   // rest / R
            int oy   = rest - c * R;                        // rest % R
            int y0 = dti0[oy], y1 = dti1[oy], x0 = dti0[ox], x1 = dti1[ox];
            float wy0 = dtw0[oy], wy1 = dtw1[oy], wx0 = dtw0[ox], wx1 = dtw1[ox];
            const float* fc = f_l + c * 256;
            float a00 = fc[y0 * 16 + x0], a01 = fc[y0 * 16 + x1];
            float a10 = fc[y1 * 16 + x0], a11 = fc[y1 * 16 + x1];
            float t0 = __fadd_rn(__fmul_rn(wy0, a00), __fmul_rn(wy1, a10));
            float t1 = __fadd_rn(__fmul_rn(wy0, a01), __fmul_rn(wy1, a11));
            float v  = __fadd_rn(__fmul_rn(wx0, t0), __fmul_rn(wx1, t1));
            bool is8 = (c < 3);
            float hl   = is8 ? HL8 : HL5;
            float offc = is8 ? 0.5f : 0.0f;
            float sh   = is8 ? SH8 : 0.0f;
            float arg  = __fadd_rn(v, sh);
            float th   = (float)tanh((double)arg);  // boundary-critical: keep exact
            float bounded = __fsub_rn(__fmul_rn(th, hl), offc);
            float q = __fmul_rn(rintf(bounded), is8 ? 0.25f : 0.5f);
            outb[off + t] = q;
            if (!last) r_pad[c * 196 + (oy + 1) * 14 + (ox + 1)] = q;
        }
        if (last) break;
        __syncthreads();

        // --- S2: conv3x3 (6->48) + GELU; wave wv owns ch [12wv,12wv+12),
        //     grouped 3 x 4-channel, one conflict-free float4 write per group ---
        const float* w1s = w1g + (size_t)s * 2592;
        const float* b1s = b1g + (size_t)s * 48;
        for (int pb = 0; pb < HW; pb += 64) {
            int p = pb + lane;
            bool act = p < HW;
            int pc = act ? p : 0;
            int py = (int)(((unsigned)pc * M) >> 20);
            int px = pc - py * R;
            int pbase = py * 14 + px;          // top-left of 3x3 patch (padded coords)
            int q = pbase + 15;                // own padded position
            float patch[6][9];
            #pragma unroll
            for (int ci = 0; ci < 6; ++ci) {
                const float* rp = r_pad + ci * 196 + pbase;
                #pragma unroll
                for (int dy = 0; dy < 3; ++dy) {
                    patch[ci][dy * 3 + 0] = rp[dy * 14 + 0];
                    patch[ci][dy * 3 + 1] = rp[dy * 14 + 1];
                    patch[ci][dy * 3 + 2] = rp[dy * 14 + 2];
                }
            }
            for (int g = 0; g < 3; ++g) {
                int kb = wv * 12 + g * 4;              // wave-uniform -> s_load weights
                const float* wk0 = w1s + (kb + 0) * 54;
                const float* wk1 = w1s + (kb + 1) * 54;
                const float* wk2 = w1s + (kb + 2) * 54;
                const float* wk3 = w1s + (kb + 3) * 54;
                float a0 = 0.f, a1 = 0.f, a2 = 0.f, a3 = 0.f;
                #pragma unroll
                for (int ci = 0; ci < 6; ++ci)
                    #pragma unroll
                    for (int j = 0; j < 9; ++j) {
                        float pv = patch[ci][j];
                        int wi = ci * 9 + j;           // same per-channel sum order
                        a0 = __fmaf_rn(wk0[wi], pv, a0);
                        a1 = __fmaf_rn(wk1[wi], pv, a1);
                        a2 = __fmaf_rn(wk2[wi], pv, a2);
                        a3 = __fmaf_rn(wk3[wi], pv, a3);
                    }
                float4 hv;
                hv.x = gelu_exact(__fadd_rn(a0, b1s[kb + 0]));
                hv.y = gelu_exact(__fadd_rn(a1, b1s[kb + 1]));
                hv.z = gelu_exact(__fadd_rn(a2, b1s[kb + 2]));
                hv.w = gelu_exact(__fadd_rn(a3, b1s[kb + 3]));
                if (act) {
                    int c4u = wv * 3 + g;              // uniform group index
                    *(float4*)&h4[(c4u * 196 + q) * 4] = hv;
                }
            }
        }
        __syncthreads();

        // --- S3: conv3x3 (48->6); thread = position, conflict-free b128 reads;
        //     weights from w2T in exact consumption order (contiguous SMEM) ---
        const float* w2sT = w2t + (size_t)s * 2592;
        const float* b2s  = b2g + (size_t)s * 6;
        {
            int p = tid;                 // HW <= 256: single round
            if (p < HW) {                // dead waves skip via execz
                int py = (int)(((unsigned)p * M) >> 20);
                int px = p - py * R;
                float acc[6];
                #pragma unroll
                for (int co = 0; co < 6; ++co) acc[co] = 0.0f;
                for (int dy = 0; dy < 3; ++dy) {
                    for (int dx = 0; dx < 3; ++dx) {
                        int qq = (py + dy) * 14 + (px + dx);
                        const float* wjt = w2sT + (dy * 3 + dx) * 288;
                        #pragma unroll 2
                        for (int c4 = 0; c4 < 12; ++c4) {
                            float4 v = *(const float4*)&h4[(c4 * 196 + qq) * 4];
                            const float* wc = wjt + c4 * 24;   // [co][e] block
                            #pragma unroll
                            for (int co = 0; co < 6; ++co) {
                                acc[co] = __fmaf_rn(wc[co * 4 + 0], v.x, acc[co]);
                                acc[co] = __fmaf_rn(wc[co * 4 + 1], v.y, acc[co]);
                                acc[co] = __fmaf_rn(wc[co * 4 + 2], v.z, acc[co]);
                                acc[co] = __fmaf_rn(wc[co * 4 + 3], v.w, acc[co]);
                            }
                        }
                    }
                }
                #pragma unroll
                for (int co = 0; co < 6; ++co)
                    z_l[co * HW + p] = __fadd_rn(acc[co], b2s[co]);
            }
        }
        __syncthreads();

        // --- S4: f -= upsample(z, 16x16) ---
        for (int t = tid; t < 1536; t += NTHREADS) {
            int x = t & 15; int y = (t >> 4) & 15; int c = t >> 8;
            int y0 = uti0[y], y1 = uti1[y], x0 = uti0[x], x1 = uti1[x];
            float wy0 = utw0[y], wy1 = utw1[y], wx0 = utw0[x], wx1 = utw1[x];
            const float* zc = z_l + c * HW;
            float a00 = zc[y0 * R + x0], a01 = zc[y0 * R + x1];
            float a10 = zc[y1 * R + x0], a11 = zc[y1 * R + x1];
            float t0 = __fadd_rn(__fmul_rn(wy0, a00), __fmul_rn(wy1, a10));
            float t1 = __fadd_rn(__fmul_rn(wy0, a01), __fmul_rn(wy1, a11));
            float zv = __fadd_rn(__fmul_rn(wx0, t0), __fmul_rn(wx1, t1));
            f_l[t] = __fsub_rn(f_l[t], zv);
        }
        __syncthreads();
    }
}

extern "C" void kernel_launch(void* const* d_in, const int* in_sizes, int n_in,
                              void* d_out, int out_size, void* d_ws, size_t ws_size,
                              hipStream_t stream) {
    const float* latents = (const float*)d_in[0];
    const float* w1 = (const float*)d_in[1];
    const float* b1 = (const float*)d_in[2];
    const float* w2 = (const float*)d_in[3];
    const float* b2 = (const float*)d_in[4];
    float* out = (float*)d_out;
    float* w2t = (float*)d_ws;   // 8*2592 floats = 82944 B scratch
    int nitems = in_sizes[0] / 1536;   // B * 6*16*16

    prep_w2t_kernel<<<40, 256, 0, stream>>>(w2, w2t);
    var_tokenizer_kernel<<<nitems, NTHREADS, 0, stream>>>(latents, w1, b1, w2t, b2, out);
}

// Round 9
// 793.758 us; speedup vs baseline: 1.0307x; 1.0307x over previous
//
#include <hip/hip_runtime.h>
#include <math.h>

#define NTHREADS 256

__constant__ int c_RESA[8] = {1, 2, 4, 6, 8, 10, 12, 16};
__constant__ int c_OFF6[8] = {0, 6, 30, 126, 342, 726, 1326, 2190};
// ceil(2^20 / R): exact floor-div for t < 2048 (verified for all R here)
__constant__ unsigned c_MAGIC[8] = {1048576u, 524288u, 262144u, 174763u,
                                    131072u, 104858u, 87382u, 65536u};

// Transpose w2 [s][co][ci][j] -> w2T [s][j][ci/4][co][ci%4] : contiguous in
// S3's exact consumption order so weight reads become mergeable s_load runs.
__global__ void __launch_bounds__(256)
prep_w2t_kernel(const float* __restrict__ w2g, float* __restrict__ w2t) {
    int tid = blockIdx.x * blockDim.x + threadIdx.x;
    for (int i = tid; i < 8 * 2592; i += gridDim.x * blockDim.x) {
        int e  = i & 3;
        int r  = i >> 2;
        int co = r % 6;  r /= 6;
        int c4 = r % 12; r /= 12;
        int j  = r % 9;
        int s  = r / 9;
        int ci = c4 * 4 + e;
        w2t[i] = w2g[((size_t)(s * 6 + co) * 48 + ci) * 9 + j];
    }
}

// Bilinear tap, matching jax.image.resize(bilinear, antialias=False).
__device__ __forceinline__ void mk_tap(int o, float invs, int insz,
                                       int* i0, int* i1, float* w0, float* w1) {
    float fy = __fsub_rn(__fmul_rn(__fadd_rn((float)o, 0.5f), invs), 0.5f);
    float fl = floorf(fy);
    int y0 = (int)fl;
    float k0 = __fsub_rn(1.0f, fabsf(__fsub_rn(fy, fl)));
    float k1 = __fsub_rn(1.0f, fabsf(__fsub_rn(fy, __fadd_rn(fl, 1.0f))));
    bool v0 = (y0 >= 0);
    bool v1 = (y0 + 1 <= insz - 1);
    k0 = v0 ? k0 : 0.0f;
    k1 = v1 ? k1 : 0.0f;
    float ssum = __fadd_rn(k0, k1);
    *w0 = __fdiv_rn(k0, ssum);
    *w1 = __fdiv_rn(k1, ssum);
    *i0 = v0 ? y0 : 0;
    *i1 = v1 ? (y0 + 1) : (insz - 1);
}

__device__ __forceinline__ float gelu_exact(float x) {
    // 0.5*x*(1+erf(x*rn(1/sqrt2))): <=1ulp vs fdiv form; proven flip-safe.
    return __fmul_rn(__fmul_rn(0.5f, x),
                     __fadd_rn(1.0f, erff(__fmul_rn(x, 0.70710678118654752440f))));
}

__global__ void __launch_bounds__(NTHREADS)
var_tokenizer_kernel(const float* __restrict__ latents,
                     const float* __restrict__ w1g, const float* __restrict__ b1g,
                     const float* __restrict__ w2t, const float* __restrict__ b2g,
                     float* __restrict__ out) {
    __shared__ float f_l[1536];                      // residual latent 6x16x16
    __shared__ float r_pad[6 * 196];                 // codes, ch-major, zero-padded 14x14
    __shared__ __align__(16) float h4[12 * 196 * 4]; // hidden: [c4-group][pos][4] float4
    __shared__ float z_l[6 * 144];                   // conv2 output (unpadded)
    __shared__ int   dti0[16]; __shared__ int dti1[16];
    __shared__ float dtw0[16]; __shared__ float dtw1[16];
    __shared__ int   uti0[16]; __shared__ int uti1[16];
    __shared__ float utw0[16]; __shared__ float utw1[16];

    const int item = blockIdx.x;
    const int tid  = threadIdx.x;
    const int wv   = __builtin_amdgcn_readfirstlane(tid >> 6); // wave id (uniform)
    const int lane = tid & 63;

    const float* lat  = latents + (size_t)item * 1536;
    float*       outb = out + (size_t)item * 3726;

    for (int i = tid; i < 1536; i += NTHREADS) f_l[i] = lat[i];
    // One-time zero fill (monotonic-resolution argument: border cells of every
    // scale's window are never written non-zero before being read; z lives in
    // separate z_l so h4/r_pad are never polluted).
    for (int i = tid; i < 6 * 196;      i += NTHREADS) r_pad[i] = 0.0f;
    for (int i = tid; i < 12 * 196 * 4; i += NTHREADS) h4[i] = 0.0f;

    // FSQ constants, replicating reference fp32 op order.
    const float HL8 = (8.0f - 1.0f) * (1.0f + 1.0e-3f) / 2.0f;  // 3.5035
    const float HL5 = (5.0f - 1.0f) * (1.0f + 1.0e-3f) / 2.0f;  // 2.002
    const float SH8 = (float)atanh((double)(0.5f / HL8));

    __syncthreads();

    for (int s = 0; s < 8; ++s) {
        const int R  = c_RESA[s];
        const int HW = R * R;
        const unsigned M = c_MAGIC[s];
        const bool last = (s == 7);

        // --- per-scale bilinear tap tables ---
        if (tid < R) {
            float invs = __fdiv_rn(1.0f, __fdiv_rn((float)R, 16.0f));
            mk_tap(tid, invs, 16, &dti0[tid], &dti1[tid], &dtw0[tid], &dtw1[tid]);
        } else if (tid >= 64 && tid < 80 && !last) {
            int o = tid - 64;
            float invs = __fdiv_rn(1.0f, __fdiv_rn(16.0f, (float)R));
            mk_tap(o, invs, R, &uti0[o], &uti1[o], &utw0[o], &utw1[o]);
        }
        __syncthreads();

        // --- S1: resize f -> (R,R), FSQ quantize, emit tokens (+ r_pad).
        //     tanhf fast path; exact-f64 rescue only near rounding boundaries
        //     (guard 1e-4 >> max |tanhf-tanh|*hl ~ 4e-7 -> q bit-exact always) ---
        const int off = c_OFF6[s];
        #pragma unroll 2
        for (int t = tid; t < 6 * HW; t += NTHREADS) {
            int rest = (int)(((unsigned)t * M) >> 20);      // t / R
            int ox   = t - rest * R;                        // t % R
            int c    = (int)(((unsigned)rest * M) >> 20);   // rest / R
            int oy   = rest - c * R;                        // rest % R
            float v;
            if (last) {
                v = f_l[t];     // R=16 bilinear resize is the identity map
            } else {
                int y0 = dti0[oy], y1 = dti1[oy], x0 = dti0[ox], x1 = dti1[ox];
                float wy0 = dtw0[oy], wy1 = dtw1[oy], wx0 = dtw0[ox], wx1 = dtw1[ox];
                const float* fc = f_l + c * 256;
                float a00 = fc[y0 * 16 + x0], a01 = fc[y0 * 16 + x1];
                float a10 = fc[y1 * 16 + x0], a11 = fc[y1 * 16 + x1];
                float t0 = __fadd_rn(__fmul_rn(wy0, a00), __fmul_rn(wy1, a10));
                float t1 = __fadd_rn(__fmul_rn(wy0, a01), __fmul_rn(wy1, a11));
                v = __fadd_rn(__fmul_rn(wx0, t0), __fmul_rn(wx1, t1));
            }
            bool is8 = (c < 3);
            float hl   = is8 ? HL8 : HL5;
            float offc = is8 ? 0.5f : 0.0f;
            float sh   = is8 ? SH8 : 0.0f;
            float arg  = __fadd_rn(v, sh);
            float th32 = tanhf(arg);
            float b32  = __fsub_rn(__fmul_rn(th32, hl), offc);
            float r32  = rintf(b32);
            float d    = __fsub_rn(b32, r32);               // in [-0.5, 0.5]
            if (fabsf(fabsf(d) - 0.5f) < 1e-4f) {           // near boundary: exact redo
                float th = (float)tanh((double)arg);
                r32 = rintf(__fsub_rn(__fmul_rn(th, hl), offc));
            }
            float q = __fmul_rn(r32, is8 ? 0.25f : 0.5f);
            outb[off + t] = q;
            if (!last) r_pad[c * 196 + (oy + 1) * 14 + (ox + 1)] = q;
        }
        if (last) break;
        __syncthreads();

        // --- S2: conv3x3 (6->48) + GELU; wave wv owns ch [12wv,12wv+12),
        //     grouped 3 x 4-channel, one conflict-free float4 write per group ---
        const float* w1s = w1g + (size_t)s * 2592;
        const float* b1s = b1g + (size_t)s * 48;
        for (int pb = 0; pb < HW; pb += 64) {
            int p = pb + lane;
            bool act = p < HW;
            int pc = act ? p : 0;
            int py = (int)(((unsigned)pc * M) >> 20);
            int px = pc - py * R;
            int pbase = py * 14 + px;          // top-left of 3x3 patch (padded coords)
            int q = pbase + 15;                // own padded position
            float patch[6][9];
            #pragma unroll
            for (int ci = 0; ci < 6; ++ci) {
                const float* rp = r_pad + ci * 196 + pbase;
                #pragma unroll
                for (int dy = 0; dy < 3; ++dy) {
                    patch[ci][dy * 3 + 0] = rp[dy * 14 + 0];
                    patch[ci][dy * 3 + 1] = rp[dy * 14 + 1];
                    patch[ci][dy * 3 + 2] = rp[dy * 14 + 2];
                }
            }
            for (int g = 0; g < 3; ++g) {
                int kb = wv * 12 + g * 4;              // wave-uniform -> s_load weights
                const float* wk0 = w1s + (kb + 0) * 54;
                const float* wk1 = w1s + (kb + 1) * 54;
                const float* wk2 = w1s + (kb + 2) * 54;
                const float* wk3 = w1s + (kb + 3) * 54;
                float a0 = 0.f, a1 = 0.f, a2 = 0.f, a3 = 0.f;
                #pragma unroll
                for (int ci = 0; ci < 6; ++ci)
                    #pragma unroll
                    for (int j = 0; j < 9; ++j) {
                        float pv = patch[ci][j];
                        int wi = ci * 9 + j;           // same per-channel sum order
                        a0 = __fmaf_rn(wk0[wi], pv, a0);
                        a1 = __fmaf_rn(wk1[wi], pv, a1);
                        a2 = __fmaf_rn(wk2[wi], pv, a2);
                        a3 = __fmaf_rn(wk3[wi], pv, a3);
                    }
                float4 hv;
                hv.x = gelu_exact(__fadd_rn(a0, b1s[kb + 0]));
                hv.y = gelu_exact(__fadd_rn(a1, b1s[kb + 1]));
                hv.z = gelu_exact(__fadd_rn(a2, b1s[kb + 2]));
                hv.w = gelu_exact(__fadd_rn(a3, b1s[kb + 3]));
                if (act) {
                    int c4u = wv * 3 + g;              // uniform group index
                    *(float4*)&h4[(c4u * 196 + q) * 4] = hv;
                }
            }
        }
        __syncthreads();

        // --- S3: conv3x3 (48->6); thread = position, conflict-free b128 reads;
        //     weights from w2T in exact consumption order (contiguous SMEM) ---
        const float* w2sT = w2t + (size_t)s * 2592;
        const float* b2s  = b2g + (size_t)s * 6;
        {
            int p = tid;                 // HW <= 256: single round
            if (p < HW) {                // dead waves skip via execz
                int py = (int)(((unsigned)p * M) >> 20);
                int px = p - py * R;
                float acc[6];
                #pragma unroll
                for (int co = 0; co < 6; ++co) acc[co] = 0.0f;
                for (int dy = 0; dy < 3; ++dy) {
                    for (int dx = 0; dx < 3; ++dx) {
                        int qq = (py + dy) * 14 + (px + dx);
                        const float* wjt = w2sT + (dy * 3 + dx) * 288;
                        #pragma unroll 2
                        for (int c4 = 0; c4 < 12; ++c4) {
                            float4 v = *(const float4*)&h4[(c4 * 196 + qq) * 4];
                            const float* wc = wjt + c4 * 24;   // [co][e] block
                            #pragma unroll
                            for (int co = 0; co < 6; ++co) {
                                acc[co] = __fmaf_rn(wc[co * 4 + 0], v.x, acc[co]);
                                acc[co] = __fmaf_rn(wc[co * 4 + 1], v.y, acc[co]);
                                acc[co] = __fmaf_rn(wc[co * 4 + 2], v.z, acc[co]);
                                acc[co] = __fmaf_rn(wc[co * 4 + 3], v.w, acc[co]);
                            }
                        }
                    }
                }
                #pragma unroll
                for (int co = 0; co < 6; ++co)
                    z_l[co * HW + p] = __fadd_rn(acc[co], b2s[co]);
            }
        }
        __syncthreads();

        // --- S4: f -= upsample(z, 16x16) ---
        for (int t = tid; t < 1536; t += NTHREADS) {
            int x = t & 15; int y = (t >> 4) & 15; int c = t >> 8;
            int y0 = uti0[y], y1 = uti1[y], x0 = uti0[x], x1 = uti1[x];
            float wy0 = utw0[y], wy1 = utw1[y], wx0 = utw0[x], wx1 = utw1[x];
            const float* zc = z_l + c * HW;
            float a00 = zc[y0 * R + x0], a01 = zc[y0 * R + x1];
            float a10 = zc[y1 * R + x0], a11 = zc[y1 * R + x1];
            float t0 = __fadd_rn(__fmul_rn(wy0, a00), __fmul_rn(wy1, a10));
            float t1 = __fadd_rn(__fmul_rn(wy0, a01), __fmul_rn(wy1, a11));
            float zv = __fadd_rn(__fmul_rn(wx0, t0), __fmul_rn(wx1, t1));
            f_l[t] = __fsub_rn(f_l[t], zv);
        }
        __syncthreads();
    }
}

extern "C" void kernel_launch(void* const* d_in, const int* in_sizes, int n_in,
                              void* d_out, int out_size, void* d_ws, size_t ws_size,
                              hipStream_t stream) {
    const float* latents = (const float*)d_in[0];
    const float* w1 = (const float*)d_in[1];
    const float* b1 = (const float*)d_in[2];
    const float* w2 = (const float*)d_in[3];
    const float* b2 = (const float*)d_in[4];
    float* out = (float*)d_out;
    float* w2t = (float*)d_ws;   // 8*2592 floats = 82944 B scratch
    int nitems = in_sizes[0] / 1536;   // B * 6*16*16

    prep_w2t_kernel<<<40, 256, 0, stream>>>(w2, w2t);
    var_tokenizer_kernel<<<nitems, NTHREADS, 0, stream>>>(latents, w1, b1, w2t, b2, out);
}